// Round 5
// baseline (44.057 us; speedup 1.0000x reference)
//
#include <hip/hip_runtime.h>
#include <math.h>

#define N_ROWS 8192
#define D 16
#define TILE 128
#define NT 64            /* 8192/128 */
#define NTILES 2080      /* NT*(NT+1)/2 upper-tri tiles */
#define GQ 2             /* tiles per block */
#define NBLOCKS 1040     /* NTILES / GQ */

/* workspace layout (bytes) */
#define OFF_CTRL 0            /* int ctrl[16]: [0]=done_ctr, [1..6]=family cnt */
#define OFF_PT   4096         /* float  pt[1040] */
#define OFF_PS   12288        /* float  ps[1040] */
#define OFF_SQ   20480        /* float  sq[8192] */
#define OFF_FA   53248        /* float  fa[8192] */
#define OFF_FB   86016        /* float  fb[8192] */
#define OFF_EHI  118784       /* ushort ehi[8192*16] (256KB) */
#define OFF_ELO  380928       /* ushort elo[8192*16] (256KB) */

typedef short  bf16x8 __attribute__((ext_vector_type(8)));
typedef float  f32x4  __attribute__((ext_vector_type(4)));

#if __has_builtin(__builtin_amdgcn_sqrtf)
#define SQRTF(x) __builtin_amdgcn_sqrtf(x)
#else
#define SQRTF(x) sqrtf(x)
#endif

/* codon index -> biosynthetic family id (K resolves to aspartate; '*' -> -1)
   families: 0=glutamate 1=aspartate 2=serine 3=pyruvate 4=aromatic 5=histidine */
__device__ __constant__ signed char FAM_LUT[64] = {
  4,4,3,3, 3,3,3,3,   /* UUU..CUG: F F L L L L L L */
  1,1,1,1, 3,3,3,3,   /* AUU..GUG: I I I M V V V V */
  2,2,2,2, 0,0,0,0,   /* UCU..CCG: S S S S P P P P */
  1,1,1,1, 3,3,3,3,   /* ACU..GCG: T T T T A A A A */
  4,4,-1,-1, 5,5,0,0, /* UAU..CAG: Y Y * * H H Q Q */
  1,1,1,1, 1,1,0,0,   /* AAU..GAG: N N K K D D E E */
  2,2,-1,4, 0,0,0,0,  /* UGU..CGG: C C * W R R R R */
  2,2,0,0, 2,2,2,2    /* AGU..GGG: S S R R G G G G */
};

__device__ __forceinline__ unsigned short f2bf(float f) {   /* RNE, finite inputs */
  unsigned u = __float_as_uint(f);
  u += 0x7fffu + ((u >> 16) & 1u);
  return (unsigned short)(u >> 16);
}
__device__ __forceinline__ float bf2f(unsigned short s) {
  return __uint_as_float((unsigned)s << 16);
}

/* prep: per-row |e|^2, family floats, bf16 hi/lo split, family histogram */
__global__ __launch_bounds__(256) void prep_kernel(
    const float* __restrict__ emb, const int* __restrict__ idx,
    float* __restrict__ sq, float* __restrict__ fa, float* __restrict__ fb,
    unsigned short* __restrict__ ehi, unsigned short* __restrict__ elo,
    int* __restrict__ cnt) {
  __shared__ int hist[8];
  const int t = threadIdx.x;
  if (t < 8) hist[t] = 0;
  __syncthreads();

  const int i = blockIdx.x * 256 + t;
  const float4* src = (const float4*)(emb + (size_t)i * D);
  float v[16];
  float4 a0 = src[0], a1 = src[1], a2 = src[2], a3 = src[3];
  v[0]=a0.x; v[1]=a0.y; v[2]=a0.z; v[3]=a0.w;
  v[4]=a1.x; v[5]=a1.y; v[6]=a1.z; v[7]=a1.w;
  v[8]=a2.x; v[9]=a2.y; v[10]=a2.z; v[11]=a2.w;
  v[12]=a3.x; v[13]=a3.y; v[14]=a3.z; v[15]=a3.w;

  float s = v[0] * v[0];
  unsigned short hi[16], lo[16];
#pragma unroll
  for (int k = 0; k < 16; ++k) {
    if (k) s = fmaf(v[k], v[k], s);
    hi[k] = f2bf(v[k]);
    lo[k] = f2bf(v[k] - bf2f(hi[k]));
  }
  sq[i] = s;
  {
    bf16x8* dh = (bf16x8*)(ehi + (size_t)i * 16);
    bf16x8* dl = (bf16x8*)(elo + (size_t)i * 16);
    dh[0] = *(bf16x8*)&hi[0]; dh[1] = *(bf16x8*)&hi[8];
    dl[0] = *(bf16x8*)&lo[0]; dl[1] = *(bf16x8*)&lo[8];
  }
  const int f = FAM_LUT[idx[i] & 63];
  fa[i] = (f >= 0) ? (float)f : -1.0f;  /* i-side: None = -1 */
  fb[i] = (f >= 0) ? (float)f : -2.0f;  /* j-side: None = -2 (None != None) */
  if (f >= 0) atomicAdd(&hist[f], 1);
  __syncthreads();
  if (t < 6) atomicAdd(&cnt[t], hist[t]);
}

__global__ __launch_bounds__(512, 4) void pair_kernel(
    const unsigned short* __restrict__ ehi, const unsigned short* __restrict__ elo,
    const float* __restrict__ sq,
    const float* __restrict__ fa, const float* __restrict__ fb,
    float* pt, float* ps, int* ctrl, float* out) {
  /* LDS: B tile in fragment-linear order (BH | BL), j-side scalars */
  __shared__ __align__(16) unsigned short BB[4096];  /* 8KB */
  __shared__ float2 SFJ[TILE];
  __shared__ float rT[8], rS[8];
  __shared__ double rTd[8], rSd[8];
  __shared__ int amLast;

  const int t  = threadIdx.x;
  const int w  = t >> 6;          /* wave 0..7: i-strip w */
  const int l  = t & 63;
  const int lr = l & 15;          /* fragment row/col index */
  const int g  = l >> 4;          /* k-slice group 0..3 */
  const int half = g & 1;         /* dims 0-7 vs 8-15 */
  const unsigned short* asrc = (g < 2) ? ehi : elo;   /* A pack: [hi|lo] on K */

  /* staging identity: thread t owns one 16B chunk, LDS offset t*16B */
  const int c = t & 255;
  const int mjs = c >> 5, hs = (c >> 4) & 1, lrs = c & 15;
  const unsigned short* bsrc = (t < 256) ? ehi : elo;

  const int q0 = blockIdx.x * GQ;

  /* ---- stage tile q0 into registers ---- */
  int u = q0 / 65, bx = q0 % 65;
  int it = (bx < NT - u) ? u : NT - 1 - u;
  int jt = (bx < NT - u) ? u + bx : bx - 1;

  bf16x8 bstage = *(const bf16x8*)(bsrc + (size_t)(jt * TILE + mjs * 16 + lrs) * 16 + hs * 8);
  float2 sfstage = (t < TILE) ? make_float2(sq[jt * TILE + t], fb[jt * TILE + t])
                              : make_float2(0.f, 0.f);
  bf16x8 afrag = *(const bf16x8*)(asrc + (size_t)(it * TILE + w * 16 + lr) * 16 + half * 8);
  float sqi[4], fai[4];
#pragma unroll
  for (int r = 0; r < 4; ++r) {
    const int irow = it * TILE + w * 16 + g * 4 + r;   /* C/D row = g*4+r */
    sqi[r] = sq[irow]; fai[r] = fa[irow];
  }

  float accT = 0.0f, accS = 0.0f;
#pragma unroll
  for (int qi = 0; qi < GQ; ++qi) {
    /* flush staged regs to LDS (prior readers done: end barrier of prev iter) */
    *(bf16x8*)(BB + t * 8) = bstage;
    if (t < TILE) SFJ[t] = sfstage;
    const float wgt = (it == jt) ? 1.0f : 2.0f;

    /* issue next-tile loads (overlap with this tile's compute) */
    bf16x8 afnext = afrag;
    float sqin[4], fain[4];
#pragma unroll
    for (int r = 0; r < 4; ++r) { sqin[r] = sqi[r]; fain[r] = fai[r]; }
    if (qi + 1 < GQ) {
      const int q = q0 + qi + 1;
      u = q / 65; bx = q % 65;
      const int itn = (bx < NT - u) ? u : NT - 1 - u;
      const int jtn = (bx < NT - u) ? u + bx : bx - 1;
      bstage = *(const bf16x8*)(bsrc + (size_t)(jtn * TILE + mjs * 16 + lrs) * 16 + hs * 8);
      if (t < TILE) sfstage = make_float2(sq[jtn * TILE + t], fb[jtn * TILE + t]);
      afnext = *(const bf16x8*)(asrc + (size_t)(itn * TILE + w * 16 + lr) * 16 + half * 8);
#pragma unroll
      for (int r = 0; r < 4; ++r) {
        const int irow = itn * TILE + w * 16 + g * 4 + r;
        sqin[r] = sq[irow]; fain[r] = fa[irow];
      }
      it = itn; jt = jtn;
    }
    __syncthreads();   /* staged writes visible */

    float tT = 0.0f, tS = 0.0f;
    const int bofs = (half * 16 + lr) * 8;
#pragma unroll
    for (int mj = 0; mj < 8; ++mj) {
      const bf16x8 blo = *(const bf16x8*)(BB + 2048 + mj * 256 + bofs);
      const bf16x8 bhi = *(const bf16x8*)(BB + mj * 256 + bofs);
      const float2 sfj = SFJ[mj * 16 + lr];            /* C/D col = lr */
      f32x4 acc = {0.0f, 0.0f, 0.0f, 0.0f};
      acc = __builtin_amdgcn_mfma_f32_16x16x32_bf16(afrag, blo, acc, 0, 0, 0);
      acc = __builtin_amdgcn_mfma_f32_16x16x32_bf16(afrag, bhi, acc, 0, 0, 0);
#pragma unroll
      for (int r = 0; r < 4; ++r) {
        float d2 = fmaf(-2.0f, acc[r], sqi[r] + sfj.x);
        d2 = fmaxf(d2, 0.0f);
        const float dist = SQRTF(d2);
        tT += dist;
        tS += (fai[r] == sfj.y) ? dist : 0.0f;
      }
    }
    accT = fmaf(wgt, tT, accT);
    accS = fmaf(wgt, tS, accS);
    __syncthreads();   /* all readers done before next overwrite */

    afrag = afnext;
#pragma unroll
    for (int r = 0; r < 4; ++r) { sqi[r] = sqin[r]; fai[r] = fain[r]; }
  }

  /* block reduction (fp32 partials ~1e5, fine) */
#pragma unroll
  for (int off = 32; off > 0; off >>= 1) {
    accT += __shfl_down(accT, off);
    accS += __shfl_down(accS, off);
  }
  if (l == 0) { rT[w] = accT; rS[w] = accS; }
  __syncthreads();
  if (t == 0) {
    float sT = 0.0f, sS = 0.0f;
#pragma unroll
    for (int k = 0; k < 8; ++k) { sT += rT[k]; sS += rS[k]; }
    pt[blockIdx.x] = sT;
    ps[blockIdx.x] = sS;
    __threadfence();
    amLast = (atomicAdd(ctrl, 1) == NBLOCKS - 1);
  }
  __syncthreads();
  if (!amLast) return;

  /* ---- last block: final reduction + loss ---- */
  __threadfence();   /* acquire */
  const volatile float* vpt = (const volatile float*)pt;
  const volatile float* vps = (const volatile float*)ps;
  double sT = 0.0, sS = 0.0;
  for (int k = t; k < NBLOCKS; k += 512) { sT += (double)vpt[k]; sS += (double)vps[k]; }
#pragma unroll
  for (int off = 32; off > 0; off >>= 1) {
    sT += __shfl_down(sT, off);
    sS += __shfl_down(sS, off);
  }
  if (l == 0) { rTd[w] = sT; rSd[w] = sS; }
  __syncthreads();
  if (t == 0) {
    double tot = 0.0, sam = 0.0;
#pragma unroll
    for (int k = 0; k < 8; ++k) { tot += rTd[k]; sam += rSd[k]; }
    double same_sum = 0.0;
    for (int f = 0; f < 6; ++f) { const double cc = (double)ctrl[1 + f]; same_sum += cc * cc; }
    const double total  = (double)N_ROWS * (double)N_ROWS;
    const double same_d = sam / (same_sum + 1e-10);
    const double diff_d = (tot - sam) / (total - same_sum + 1e-10);
    double loss = same_d - 0.5 * diff_d + 1.0;
    out[0] = (float)(loss > 0.0 ? loss : 0.0);
    ctrl[0] = 0;   /* reset done-counter for the next replay */
  }
}

extern "C" void kernel_launch(void* const* d_in, const int* in_sizes, int n_in,
                              void* d_out, int out_size, void* d_ws, size_t ws_size,
                              hipStream_t stream) {
  const float* emb = (const float*)d_in[0];
  const int*   idx = (const int*)d_in[1];
  char* ws = (char*)d_ws;
  int*            ctrl = (int*)(ws + OFF_CTRL);
  float*          pt   = (float*)(ws + OFF_PT);
  float*          ps   = (float*)(ws + OFF_PS);
  float*          sqv  = (float*)(ws + OFF_SQ);
  float*          fav  = (float*)(ws + OFF_FA);
  float*          fbv  = (float*)(ws + OFF_FB);
  unsigned short* ehi  = (unsigned short*)(ws + OFF_EHI);
  unsigned short* elo  = (unsigned short*)(ws + OFF_ELO);

  hipMemsetAsync(ctrl, 0, 64, stream);   /* done_ctr + family counts */
  prep_kernel<<<dim3(N_ROWS / 256), dim3(256), 0, stream>>>(
      emb, idx, sqv, fav, fbv, ehi, elo, ctrl + 1);
  pair_kernel<<<dim3(NBLOCKS), dim3(512), 0, stream>>>(
      ehi, elo, sqv, fav, fbv, pt, ps, ctrl, (float*)d_out);
}

// Round 6
// 27.195 us; speedup vs baseline: 1.6200x; 1.6200x over previous
//
#include <hip/hip_runtime.h>
#include <math.h>

#define N_ROWS 8192
#define D 16
#define TILE 128
#define NT 64            /* 8192/128 */
#define NBLK 2080        /* NT*(NT+1)/2 upper-tri tiles */

/* workspace layout (bytes) */
#define OFF_PT   0            /* float  pt[2080] */
#define OFF_PS   16384        /* float  ps[2080] */
#define OFF_SQ   32768        /* float  sq[8192] */
#define OFF_FA   65536        /* float  fa[8192] */
#define OFF_FB   98304        /* float  fb[8192] */
#define OFF_EHI  131072       /* ushort ehi[8192*16] (256KB) */
#define OFF_ELO  393216       /* ushort elo[8192*16] (256KB) */

typedef short  bf16x8 __attribute__((ext_vector_type(8)));
typedef float  f32x4  __attribute__((ext_vector_type(4)));

#if __has_builtin(__builtin_amdgcn_sqrtf)
#define SQRTF(x) __builtin_amdgcn_sqrtf(x)
#else
#define SQRTF(x) sqrtf(x)
#endif

/* codon index -> biosynthetic family id (K resolves to aspartate; '*' -> -1)
   families: 0=glutamate 1=aspartate 2=serine 3=pyruvate 4=aromatic 5=histidine */
__device__ __constant__ signed char FAM_LUT[64] = {
  4,4,3,3, 3,3,3,3,   /* UUU..CUG: F F L L L L L L */
  1,1,1,1, 3,3,3,3,   /* AUU..GUG: I I I M V V V V */
  2,2,2,2, 0,0,0,0,   /* UCU..CCG: S S S S P P P P */
  1,1,1,1, 3,3,3,3,   /* ACU..GCG: T T T T A A A A */
  4,4,-1,-1, 5,5,0,0, /* UAU..CAG: Y Y * * H H Q Q */
  1,1,1,1, 1,1,0,0,   /* AAU..GAG: N N K K D D E E */
  2,2,-1,4, 0,0,0,0,  /* UGU..CGG: C C * W R R R R */
  2,2,0,0, 2,2,2,2    /* AGU..GGG: S S R R G G G G */
};

__device__ __forceinline__ unsigned short f2bf(float f) {   /* RNE, finite inputs */
  unsigned u = __float_as_uint(f);
  u += 0x7fffu + ((u >> 16) & 1u);
  return (unsigned short)(u >> 16);
}
__device__ __forceinline__ float bf2f(unsigned short s) {
  return __uint_as_float((unsigned)s << 16);
}

/* prep: per-row |e|^2, family floats, and the global bf16 hi/lo split */
__global__ __launch_bounds__(256) void prep_kernel(
    const float* __restrict__ emb, const int* __restrict__ idx,
    float* __restrict__ sq, float* __restrict__ fa, float* __restrict__ fb,
    unsigned short* __restrict__ ehi, unsigned short* __restrict__ elo) {
  const int i = blockIdx.x * 256 + threadIdx.x;
  const float4* src = (const float4*)(emb + (size_t)i * D);
  float v[16];
  float4 a0 = src[0], a1 = src[1], a2 = src[2], a3 = src[3];
  v[0]=a0.x; v[1]=a0.y; v[2]=a0.z; v[3]=a0.w;
  v[4]=a1.x; v[5]=a1.y; v[6]=a1.z; v[7]=a1.w;
  v[8]=a2.x; v[9]=a2.y; v[10]=a2.z; v[11]=a2.w;
  v[12]=a3.x; v[13]=a3.y; v[14]=a3.z; v[15]=a3.w;

  float s = v[0] * v[0];
  unsigned short hi[16], lo[16];
#pragma unroll
  for (int k = 0; k < 16; ++k) {
    if (k) s = fmaf(v[k], v[k], s);
    hi[k] = f2bf(v[k]);
    lo[k] = f2bf(v[k] - bf2f(hi[k]));
  }
  sq[i] = s;
  {
    bf16x8* dh = (bf16x8*)(ehi + (size_t)i * 16);
    bf16x8* dl = (bf16x8*)(elo + (size_t)i * 16);
    dh[0] = *(bf16x8*)&hi[0]; dh[1] = *(bf16x8*)&hi[8];
    dl[0] = *(bf16x8*)&lo[0]; dl[1] = *(bf16x8*)&lo[8];
  }
  const int f = FAM_LUT[idx[i] & 63];
  fa[i] = (f >= 0) ? (float)f : -1.0f;  /* i-side: None = -1 */
  fb[i] = (f >= 0) ? (float)f : -2.0f;  /* j-side: None = -2 (None != None) */
}

__global__ __launch_bounds__(512, 4) void pair_kernel(
    const unsigned short* __restrict__ ehi, const unsigned short* __restrict__ elo,
    const float* __restrict__ sq,
    const float* __restrict__ fa, const float* __restrict__ fb,
    float* __restrict__ pt, float* __restrict__ ps) {
  /* triangular fold: grid (65,32) -> every block a live upper-tri 128x128 tile */
  const int u = blockIdx.y, bx = blockIdx.x;
  int it, jt;
  if (bx < NT - u) { it = u;          jt = u + bx; }
  else             { it = NT - 1 - u; jt = bx - 1; }

  /* B tile staged in MFMA fragment-linear order: [mj][half][lr] x 16B chunks */
  __shared__ __align__(16) unsigned short BH[2048];  /* 4KB */
  __shared__ __align__(16) unsigned short BL[2048];  /* 4KB */
  __shared__ float2 SFJ[TILE];                       /* x = sq_j, y = famB_j */
  __shared__ float rT[8], rS[8];

  const int t  = threadIdx.x;
  const int w  = t >> 6;          /* wave 0..7: i-strip w */
  const int l  = t & 63;
  const int lr = l & 15;          /* fragment row/col index */
  const int g  = l >> 4;          /* k-slice group 0..3 */
  const int half = g & 1;         /* dims 0-7 vs 8-15 */

  /* A fragment (pack [hi | lo] along K=32) + i-side scalars, from global/L2 */
  const unsigned short* asrc = (g < 2) ? ehi : elo;
  const int arow = it * TILE + w * 16 + lr;
  const bf16x8 afrag = *(const bf16x8*)(asrc + (size_t)arow * 16 + half * 8);
  float sqi[4], fai[4];
#pragma unroll
  for (int r = 0; r < 4; ++r) {
    const int irow = it * TILE + w * 16 + g * 4 + r;   /* C/D row = g*4+r */
    sqi[r] = sq[irow];
    fai[r] = fa[irow];
  }

  /* stage j-tile: 512 threads x one 16B chunk (waves 0-3: BH, 4-7: BL) */
  {
    const int c   = t & 255;
    const int mjs = c >> 5, hs = (c >> 4) & 1, lrs = c & 15;
    const int grow = jt * TILE + mjs * 16 + lrs;
    const unsigned short* src = (t < 256) ? ehi : elo;
    unsigned short*       dst = (t < 256) ? BH  : BL;
    *(bf16x8*)(dst + c * 8) = *(const bf16x8*)(src + (size_t)grow * 16 + hs * 8);
    if (t < TILE) SFJ[t] = make_float2(sq[jt * TILE + t], fb[jt * TILE + t]);
  }
  __syncthreads();

  const int bofs = (half * 16 + lr) * 8;   /* ushort offset within an mj-group */
  float accT = 0.0f, accS = 0.0f;
#pragma unroll 2
  for (int mj = 0; mj < 8; ++mj) {
    const bf16x8 bhi = *(const bf16x8*)(BH + mj * 256 + bofs);
    const bf16x8 blo = *(const bf16x8*)(BL + mj * 256 + bofs);
    const float2 sfj = SFJ[mj * 16 + lr];            /* C/D col = lr */
    /* B = lo replicated along K gives (hi_a+lo_a)*lo_b; then + (hi_a+lo_a)*hi_b */
    f32x4 acc = {0.0f, 0.0f, 0.0f, 0.0f};
    acc = __builtin_amdgcn_mfma_f32_16x16x32_bf16(afrag, blo, acc, 0, 0, 0);
    acc = __builtin_amdgcn_mfma_f32_16x16x32_bf16(afrag, bhi, acc, 0, 0, 0);
#pragma unroll
    for (int r = 0; r < 4; ++r) {
      float d2 = fmaf(-2.0f, acc[r], sqi[r] + sfj.x);
      d2 = fmaxf(d2, 0.0f);
      const float dist = SQRTF(d2);
      accT += dist;
      accS += (fai[r] == sfj.y) ? dist : 0.0f;
    }
  }

  /* block reduction (fp32 partials ~1e5, fine) */
#pragma unroll
  for (int off = 32; off > 0; off >>= 1) {
    accT += __shfl_down(accT, off);
    accS += __shfl_down(accS, off);
  }
  if (l == 0) { rT[w] = accT; rS[w] = accS; }
  __syncthreads();
  if (t == 0) {
    float sT = 0.0f, sS = 0.0f;
#pragma unroll
    for (int k = 0; k < 8; ++k) { sT += rT[k]; sS += rS[k]; }
    const float wgt = (it == jt) ? 1.0f : 2.0f;
    const int bid = blockIdx.y * gridDim.x + blockIdx.x;
    pt[bid] = wgt * sT;
    ps[bid] = wgt * sS;
  }
}

__global__ __launch_bounds__(1024) void final_kernel(
    const float* __restrict__ pt, const float* __restrict__ ps,
    const int* __restrict__ idx, float* __restrict__ out) {
  const int t = threadIdx.x;
  __shared__ int hist[8];
  __shared__ double rTd[16], rSd[16];
  if (t < 8) hist[t] = 0;
  __syncthreads();
  for (int k = t; k < N_ROWS; k += 1024) {
    const int f = FAM_LUT[idx[k] & 63];
    if (f >= 0) atomicAdd(&hist[f], 1);
  }

  double sT = 0.0, sS = 0.0;
  for (int k = t; k < NBLK; k += 1024) { sT += (double)pt[k]; sS += (double)ps[k]; }
#pragma unroll
  for (int off = 32; off > 0; off >>= 1) {
    sT += __shfl_down(sT, off);
    sS += __shfl_down(sS, off);
  }
  if ((t & 63) == 0) { rTd[t >> 6] = sT; rSd[t >> 6] = sS; }
  __syncthreads();
  if (t == 0) {
    double tot = 0.0, sam = 0.0;
#pragma unroll
    for (int k = 0; k < 16; ++k) { tot += rTd[k]; sam += rSd[k]; }
    double same_sum = 0.0;
    for (int f = 0; f < 6; ++f) { const double c = (double)hist[f]; same_sum += c * c; }
    const double total  = (double)N_ROWS * (double)N_ROWS;
    const double same_d = sam / (same_sum + 1e-10);
    const double diff_d = (tot - sam) / (total - same_sum + 1e-10);
    double loss = same_d - 0.5 * diff_d + 1.0;
    out[0] = (float)(loss > 0.0 ? loss : 0.0);
  }
}

extern "C" void kernel_launch(void* const* d_in, const int* in_sizes, int n_in,
                              void* d_out, int out_size, void* d_ws, size_t ws_size,
                              hipStream_t stream) {
  const float* emb = (const float*)d_in[0];
  const int*   idx = (const int*)d_in[1];
  char* ws = (char*)d_ws;
  float*          pt  = (float*)(ws + OFF_PT);
  float*          ps  = (float*)(ws + OFF_PS);
  float*          sqv = (float*)(ws + OFF_SQ);
  float*          fav = (float*)(ws + OFF_FA);
  float*          fbv = (float*)(ws + OFF_FB);
  unsigned short* ehi = (unsigned short*)(ws + OFF_EHI);
  unsigned short* elo = (unsigned short*)(ws + OFF_ELO);

  prep_kernel<<<dim3(N_ROWS / 256), dim3(256), 0, stream>>>(emb, idx, sqv, fav, fbv, ehi, elo);
  pair_kernel<<<dim3(NT + 1, NT / 2), dim3(512), 0, stream>>>(ehi, elo, sqv, fav, fbv, pt, ps);
  final_kernel<<<dim3(1), dim3(1024), 0, stream>>>(pt, ps, idx, (float*)d_out);
}

// Round 7
// 27.022 us; speedup vs baseline: 1.6304x; 1.0064x over previous
//
#include <hip/hip_runtime.h>
#include <math.h>

#define N_ROWS 8192
#define D 16
#define TILE 128
#define NT 64            /* 8192/128 */
#define NBLK 2080        /* NT*(NT+1)/2 upper-tri tiles */

/* workspace layout (bytes) */
#define OFF_PT   0            /* float pt[2080] */
#define OFF_PS   16384        /* float ps[2080] */

typedef short  bf16x8 __attribute__((ext_vector_type(8)));
typedef float  f32x4  __attribute__((ext_vector_type(4)));

#if __has_builtin(__builtin_amdgcn_sqrtf)
#define SQRTF(x) __builtin_amdgcn_sqrtf(x)
#else
#define SQRTF(x) sqrtf(x)
#endif

/* codon index -> biosynthetic family id (K resolves to aspartate; '*' -> -1)
   families: 0=glutamate 1=aspartate 2=serine 3=pyruvate 4=aromatic 5=histidine */
__device__ __constant__ signed char FAM_LUT[64] = {
  4,4,3,3, 3,3,3,3,   /* UUU..CUG: F F L L L L L L */
  1,1,1,1, 3,3,3,3,   /* AUU..GUG: I I I M V V V V */
  2,2,2,2, 0,0,0,0,   /* UCU..CCG: S S S S P P P P */
  1,1,1,1, 3,3,3,3,   /* ACU..GCG: T T T T A A A A */
  4,4,-1,-1, 5,5,0,0, /* UAU..CAG: Y Y * * H H Q Q */
  1,1,1,1, 1,1,0,0,   /* AAU..GAG: N N K K D D E E */
  2,2,-1,4, 0,0,0,0,  /* UGU..CGG: C C * W R R R R */
  2,2,0,0, 2,2,2,2    /* AGU..GGG: S S R R G G G G */
};

__device__ __forceinline__ unsigned short f2bf(float f) {   /* RNE, finite inputs */
  unsigned u = __float_as_uint(f);
  u += 0x7fffu + ((u >> 16) & 1u);
  return (unsigned short)(u >> 16);
}
__device__ __forceinline__ float bf2f(unsigned short s) {
  return __uint_as_float((unsigned)s << 16);
}

__global__ __launch_bounds__(512, 4) void pair_kernel(
    const float* __restrict__ emb, const int* __restrict__ idx,
    float* __restrict__ pt, float* __restrict__ ps) {
  /* triangular fold: grid (65,32) -> every block a live upper-tri 128x128 tile */
  const int u = blockIdx.y, bx = blockIdx.x;
  int it, jt;
  if (bx < NT - u) { it = u;          jt = u + bx; }
  else             { it = NT - 1 - u; jt = bx - 1; }

  /* B tile in MFMA fragment-linear order: [mj][half][lr] x 16B chunks */
  __shared__ __align__(16) unsigned short BH[2048];  /* 4KB hi */
  __shared__ __align__(16) unsigned short BL[2048];  /* 4KB lo */
  __shared__ float2 SFJ[TILE];   /* x = sq_j, y = fam_j (None=-2) */
  __shared__ float  SQI[TILE];   /* sq_i */
  __shared__ float  FAI[TILE];   /* fam_i (None=-1) */
  __shared__ float  rT[8], rS[8];

  const int t  = threadIdx.x;
  const int w  = t >> 6;          /* wave 0..7: i-strip w */
  const int l  = t & 63;
  const int lr = l & 15;          /* fragment row/col index */
  const int g  = l >> 4;          /* k-slice group 0..3 */
  const int half = g & 1;         /* dims 0-7 vs 8-15 */

  /* (a) per-row scalars: t<128 -> i-side, 128<=t<256 -> j-side */
  if (t < 256) {
    const int local = t & 127;
    const int row = ((t < 128) ? it : jt) * TILE + local;
    const float4* s4 = (const float4*)(emb + (size_t)row * D);
    float4 a0 = s4[0], a1 = s4[1], a2 = s4[2], a3 = s4[3];
    float v[16];
    v[0]=a0.x; v[1]=a0.y; v[2]=a0.z; v[3]=a0.w;
    v[4]=a1.x; v[5]=a1.y; v[6]=a1.z; v[7]=a1.w;
    v[8]=a2.x; v[9]=a2.y; v[10]=a2.z; v[11]=a2.w;
    v[12]=a3.x; v[13]=a3.y; v[14]=a3.z; v[15]=a3.w;
    float ss = v[0] * v[0];
#pragma unroll
    for (int k = 1; k < 16; ++k) ss = fmaf(v[k], v[k], ss);
    const int f = FAM_LUT[idx[row] & 63];
    if (t < 128) { SQI[local] = ss; FAI[local] = (f >= 0) ? (float)f : -1.0f; }
    else         { SFJ[local] = make_float2(ss, (f >= 0) ? (float)f : -2.0f); }
  }

  /* (b) B-tile hi/lo conversion + staging: t<256, one 16B chunk each */
  if (t < 256) {
    const int mjs = t >> 5, hs = (t >> 4) & 1, lrs = t & 15;
    const int row = jt * TILE + mjs * 16 + lrs;
    const float4* s4 = (const float4*)(emb + (size_t)row * D + hs * 8);
    float4 b0 = s4[0], b1 = s4[1];
    float vb[8];
    vb[0]=b0.x; vb[1]=b0.y; vb[2]=b0.z; vb[3]=b0.w;
    vb[4]=b1.x; vb[5]=b1.y; vb[6]=b1.z; vb[7]=b1.w;
    unsigned short h8[8], l8[8];
#pragma unroll
    for (int k = 0; k < 8; ++k) {
      h8[k] = f2bf(vb[k]);
      l8[k] = f2bf(vb[k] - bf2f(h8[k]));
    }
    *(bf16x8*)(BH + t * 8) = *(bf16x8*)h8;
    *(bf16x8*)(BL + t * 8) = *(bf16x8*)l8;
  }

  /* (c) A fragment ([hi|lo] along K=32): direct from raw f32 */
  const int arow = it * TILE + w * 16 + lr;
  const float4* a4 = (const float4*)(emb + (size_t)arow * D + half * 8);
  float4 c0 = a4[0], c1 = a4[1];
  float va[8];
  va[0]=c0.x; va[1]=c0.y; va[2]=c0.z; va[3]=c0.w;
  va[4]=c1.x; va[5]=c1.y; va[6]=c1.z; va[7]=c1.w;
  unsigned short f8[8];
#pragma unroll
  for (int k = 0; k < 8; ++k) {
    const unsigned short h = f2bf(va[k]);
    f8[k] = (g < 2) ? h : f2bf(va[k] - bf2f(h));
  }
  const bf16x8 afrag = *(bf16x8*)f8;

  __syncthreads();

  float sqi[4], fai[4];
#pragma unroll
  for (int r = 0; r < 4; ++r) {
    sqi[r] = SQI[w * 16 + g * 4 + r];   /* C/D row = g*4+r */
    fai[r] = FAI[w * 16 + g * 4 + r];
  }

  const int bofs = (half * 16 + lr) * 8;   /* ushort offset within an mj-group */
  float accT = 0.0f, accS = 0.0f;
#pragma unroll 2
  for (int mj = 0; mj < 8; ++mj) {
    const bf16x8 bhi = *(const bf16x8*)(BH + mj * 256 + bofs);
    const bf16x8 blo = *(const bf16x8*)(BL + mj * 256 + bofs);
    const float2 sfj = SFJ[mj * 16 + lr];            /* C/D col = lr */
    /* B = lo replicated along K gives (hi_a+lo_a)*lo_b; then + (hi_a+lo_a)*hi_b */
    f32x4 acc = {0.0f, 0.0f, 0.0f, 0.0f};
    acc = __builtin_amdgcn_mfma_f32_16x16x32_bf16(afrag, blo, acc, 0, 0, 0);
    acc = __builtin_amdgcn_mfma_f32_16x16x32_bf16(afrag, bhi, acc, 0, 0, 0);
#pragma unroll
    for (int r = 0; r < 4; ++r) {
      float d2 = fmaf(-2.0f, acc[r], sqi[r] + sfj.x);
      d2 = fmaxf(d2, 0.0f);
      const float dist = SQRTF(d2);
      accT += dist;
      accS += (fai[r] == sfj.y) ? dist : 0.0f;
    }
  }

  /* block reduction (fp32 partials ~1e5, fine) */
#pragma unroll
  for (int off = 32; off > 0; off >>= 1) {
    accT += __shfl_down(accT, off);
    accS += __shfl_down(accS, off);
  }
  if (l == 0) { rT[w] = accT; rS[w] = accS; }
  __syncthreads();
  if (t == 0) {
    float sT = 0.0f, sS = 0.0f;
#pragma unroll
    for (int k = 0; k < 8; ++k) { sT += rT[k]; sS += rS[k]; }
    const float wgt = (it == jt) ? 1.0f : 2.0f;
    const int bid = blockIdx.y * gridDim.x + blockIdx.x;
    pt[bid] = wgt * sT;
    ps[bid] = wgt * sS;
  }
}

__global__ __launch_bounds__(512) void final_kernel(
    const float* __restrict__ pt, const float* __restrict__ ps,
    const int* __restrict__ idx, float* __restrict__ out) {
  const int t = threadIdx.x, w = t >> 6, l = t & 63;
  __shared__ float  HW[8][8];    /* per-wave family counts */
  __shared__ double rTd[8], rSd[8];

  /* ballot histogram: no atomics, 8192 items over 8 waves x 16 rounds */
  float myCnt = 0.0f;            /* lane f (<6) counts family f */
#pragma unroll
  for (int rr = 0; rr < 16; ++rr) {
    const int f = FAM_LUT[idx[rr * 512 + t] & 63];
#pragma unroll
    for (int fam = 0; fam < 6; ++fam) {
      const unsigned long long m = __ballot(f == fam);
      if (l == fam) myCnt += (float)__popcll(m);
    }
  }
  if (l < 8) HW[w][l] = (l < 6) ? myCnt : 0.0f;

  double sT = 0.0, sS = 0.0;
  for (int k = t; k < NBLK; k += 512) { sT += (double)pt[k]; sS += (double)ps[k]; }
#pragma unroll
  for (int off = 32; off > 0; off >>= 1) {
    sT += __shfl_down(sT, off);
    sS += __shfl_down(sS, off);
  }
  if (l == 0) { rTd[w] = sT; rSd[w] = sS; }
  __syncthreads();
  if (t == 0) {
    double tot = 0.0, sam = 0.0;
#pragma unroll
    for (int k = 0; k < 8; ++k) { tot += rTd[k]; sam += rSd[k]; }
    double same_sum = 0.0;
    for (int f = 0; f < 6; ++f) {
      double c = 0.0;
      for (int k = 0; k < 8; ++k) c += (double)HW[k][f];
      same_sum += c * c;
    }
    const double total  = (double)N_ROWS * (double)N_ROWS;
    const double same_d = sam / (same_sum + 1e-10);
    const double diff_d = (tot - sam) / (total - same_sum + 1e-10);
    double loss = same_d - 0.5 * diff_d + 1.0;
    out[0] = (float)(loss > 0.0 ? loss : 0.0);
  }
}

extern "C" void kernel_launch(void* const* d_in, const int* in_sizes, int n_in,
                              void* d_out, int out_size, void* d_ws, size_t ws_size,
                              hipStream_t stream) {
  const float* emb = (const float*)d_in[0];
  const int*   idx = (const int*)d_in[1];
  char* ws = (char*)d_ws;
  float* pt = (float*)(ws + OFF_PT);
  float* ps = (float*)(ws + OFF_PS);

  pair_kernel<<<dim3(NT + 1, NT / 2), dim3(512), 0, stream>>>(emb, idx, pt, ps);
  final_kernel<<<dim3(1), dim3(512), 0, stream>>>(pt, ps, idx, (float*)d_out);
}